// Round 5
// baseline (189.057 us; speedup 1.0000x reference)
//
#include <hip/hip_runtime.h>
#include <hip/hip_bf16.h>

// BERT self-attention, B=8 S=1024 D=768 H=12 DH=64, fp32 in/out.
// (1) bf16 MFMA projection GEMM -> mixed (row-major) + mixedT ([b][h][d][t]).
// (2) flash attention: QB=64 x KVB=128 phases, 4 waves x 16 q-rows,
//     XOR-swizzled LDS (verified conflict-free), reg-prefetch (T14),
//     XCD-grouped block swizzle (T1), defer-max (T13), exp2 softmax.

#define D_MODEL 768
#define SEQ     1024
#define NHEAD   12
#define DHEAD   64
#define BATCH   8
#define QB      64
#define KVB     128
#define LOG2E   1.44269504088896f

typedef __attribute__((ext_vector_type(8))) short bf16x8;
typedef __attribute__((ext_vector_type(4))) short short4v;
typedef __attribute__((ext_vector_type(4))) float f32x4;

__device__ __forceinline__ unsigned short f2bf(float f) {
  __hip_bfloat16 h = __float2bfloat16(f);
  return *reinterpret_cast<unsigned short*>(&h);
}

__device__ __forceinline__ float fexp2(float x) {
#if __has_builtin(__builtin_amdgcn_exp2f)
  return __builtin_amdgcn_exp2f(x);
#else
  return exp2f(x);
#endif
}

// 64-wide bf16 tile: elem-index XOR swizzle (16B granule x row)
__device__ __forceinline__ int swzK(int r, int c) {
  return (r << 6) + (c ^ ((r & 7) << 3));
}
// 128-wide bf16 tile [d][t]
__device__ __forceinline__ int swzT(int d, int t) {
  return (d << 7) + (t ^ ((d & 15) << 3));
}

// ---------------------------------------------------------------------------
// Projection GEMM: mixed = bf16(X @ W^T + b); also mixedT (per-head [d][t]).
// ---------------------------------------------------------------------------
template<bool WRITE_T>
__global__ __launch_bounds__(256) void proj_kernel(
    const float* __restrict__ X, const float* __restrict__ W,
    const float* __restrict__ bias, unsigned short* __restrict__ mixed,
    unsigned short* __restrict__ mixedT)
{
  __shared__ unsigned short As[128][40];
  __shared__ unsigned short Bs[128][40];

  const int tid = threadIdx.x;
  const int l   = tid & 63;
  const int w   = tid >> 6;
  const int m0  = blockIdx.x * 128;
  const int n0  = blockIdx.y * 128;
  const int wm  = (w >> 1) * 64;
  const int wn  = (w & 1) * 64;
  const int lr  = l & 15;
  const int g   = l >> 4;
  const int lk  = g * 8;

  f32x4 acc[4][4] = {};

  for (int k0 = 0; k0 < D_MODEL; k0 += 32) {
    #pragma unroll
    for (int rr = 0; rr < 4; ++rr) {
      int p   = tid + rr * 256;
      int row = p >> 3;
      int cg  = (p & 7) * 4;
      f32x4 a  = *(const f32x4*)&X[(size_t)(m0 + row) * D_MODEL + k0 + cg];
      f32x4 bv = *(const f32x4*)&W[(size_t)(n0 + row) * D_MODEL + k0 + cg];
      short4v ap, bp;
      #pragma unroll
      for (int jj = 0; jj < 4; ++jj) { ap[jj] = (short)f2bf(a[jj]); bp[jj] = (short)f2bf(bv[jj]); }
      *(short4v*)&As[row][cg] = ap;
      *(short4v*)&Bs[row][cg] = bp;
    }
    __syncthreads();

    bf16x8 af[4], bfr[4];
    #pragma unroll
    for (int am = 0; am < 4; ++am) af[am]  = *(const bf16x8*)&As[wm + am * 16 + lr][lk];
    #pragma unroll
    for (int bn = 0; bn < 4; ++bn) bfr[bn] = *(const bf16x8*)&Bs[wn + bn * 16 + lr][lk];

    #pragma unroll
    for (int am = 0; am < 4; ++am)
      #pragma unroll
      for (int bn = 0; bn < 4; ++bn)
        acc[am][bn] = __builtin_amdgcn_mfma_f32_16x16x32_bf16(
            af[am], bfr[bn], acc[am][bn], 0, 0, 0);
    __syncthreads();
  }

  const int orow = g * 4;
  const int bT   = m0 >> 10;
  const int tl0  = (m0 & 1023) + wm + orow;
  #pragma unroll
  for (int bn = 0; bn < 4; ++bn) {
    int   col  = n0 + wn + bn * 16 + lr;
    float bcol = bias[col];
    size_t tbase = ((size_t)bT * D_MODEL + col) * SEQ;
    #pragma unroll
    for (int am = 0; am < 4; ++am) {
      short4v pk;
      #pragma unroll
      for (int i = 0; i < 4; ++i) {
        float v = acc[am][bn][i] + bcol;
        unsigned short hv = f2bf(v);
        mixed[(size_t)(m0 + wm + am * 16 + orow + i) * D_MODEL + col] = hv;
        pk[i] = (short)hv;
      }
      if (WRITE_T)
        *(short4v*)&mixedT[tbase + tl0 + am * 16] = pk;
    }
  }
}

// ---------------------------------------------------------------------------
// Fused attention.
// ---------------------------------------------------------------------------
template<bool PRE_T>
__global__ __launch_bounds__(256, 4) void attn_kernel(
    const unsigned short* __restrict__ mixed,
    const unsigned short* __restrict__ mixedT,
    const float* __restrict__ mask, float* __restrict__ out)
{
  __shared__ unsigned short QP[QB * DHEAD];    //  8 KB: Q, then per-wave P
  __shared__ unsigned short Xs[KVB * DHEAD];   // 16 KB: K rows [t][d]
  __shared__ unsigned short XTs[DHEAD * KVB];  // 16 KB: V^T rows [d][t]

  const int tid = threadIdx.x;
  const int l   = tid & 63;
  const int w   = tid >> 6;
  const int lr  = l & 15;
  const int g   = l >> 4;
  const int lk  = g * 8;

  // XCD-grouped decode: all 16 q-tiles of one (b,h) share id mod 8 (same XCD)
  const int id  = blockIdx.x;          // 0..1535
  const int xcd = id & 7;
  const int j   = id >> 3;             // 0..191
  const int pr  = xcd * 12 + (j >> 4); // 0..95 (b,h) pair
  const int q0  = (j & 15) * QB;
  const int h   = pr % NHEAD;
  const int b   = pr / NHEAD;

  const size_t base  = ((size_t)b * SEQ) * D_MODEL + h * DHEAD;
  const size_t baseT = ((size_t)b * D_MODEL + h * DHEAD) * SEQ;

  // staging coords
  const int xrow = tid >> 3;           // Xs: + p*32
  const int xcol = (tid & 7) * 8;
  const int td   = tid >> 4;           // XTs: + p*16
  const int tcol = (tid & 15) * 8;

  // ---- stage Q (64x64) ----
  #pragma unroll
  for (int rr = 0; rr < 2; ++rr) {
    int row = xrow + rr * 32;
    bf16x8 v = *(const bf16x8*)&mixed[base + (size_t)(q0 + row) * D_MODEL + xcol];
    *(bf16x8*)&QP[swzK(row, xcol)] = v;
  }

  // ---- prefetch kv phase 0 ----
  bf16x8 xr[4], xtr[4];
  #pragma unroll
  for (int p = 0; p < 4; ++p) {
    xr[p] = *(const bf16x8*)&mixed[base + (size_t)(xrow + p * 32) * D_MODEL + xcol];
    if (PRE_T)
      xtr[p] = *(const bf16x8*)&mixedT[baseT + (size_t)(td + p * 16) * SEQ + tcol];
  }

  __syncthreads();
  bf16x8 qf[2];
  qf[0] = *(const bf16x8*)&QP[swzK(w * 16 + lr, lk)];
  qf[1] = *(const bf16x8*)&QP[swzK(w * 16 + lr, 32 + lk)];
  // QP rows [w*16, w*16+16) become wave-private P storage from here on.

  float m_i[4], l_i[4];
  f32x4 cacc[4] = {};
  #pragma unroll
  for (int i = 0; i < 4; ++i) { m_i[i] = -1e30f; l_i[i] = 0.f; }

  const float SCL = 0.125f * LOG2E;

  for (int t0 = 0; t0 < SEQ; t0 += KVB) {
    // ---- regs -> LDS ----
    #pragma unroll
    for (int p = 0; p < 4; ++p) {
      *(bf16x8*)&Xs[swzK(xrow + p * 32, xcol)] = xr[p];
      if (PRE_T) {
        *(bf16x8*)&XTs[swzT(td + p * 16, tcol)] = xtr[p];
      } else {
        #pragma unroll
        for (int jj = 0; jj < 8; ++jj)
          XTs[swzT(xcol + jj, xrow + p * 32)] = (unsigned short)xr[p][jj];
      }
    }
    __syncthreads();

    // ---- prefetch next phase ----
    if (t0 + KVB < SEQ) {
      #pragma unroll
      for (int p = 0; p < 4; ++p) {
        xr[p] = *(const bf16x8*)&mixed[base +
                  (size_t)(t0 + KVB + xrow + p * 32) * D_MODEL + xcol];
        if (PRE_T)
          xtr[p] = *(const bf16x8*)&mixedT[baseT +
                     (size_t)(td + p * 16) * SEQ + t0 + KVB + tcol];
      }
    }

    float mk[8];
    #pragma unroll
    for (int nf = 0; nf < 8; ++nf)
      mk[nf] = mask[(size_t)b * SEQ + t0 + nf * 16 + lr] * LOG2E;

    // ---- S = Q @ K^T (16 MFMA) ----
    f32x4 sacc[8] = {};
    #pragma unroll
    for (int kf = 0; kf < 2; ++kf)
      #pragma unroll
      for (int nf = 0; nf < 8; ++nf) {
        bf16x8 kfr = *(const bf16x8*)&Xs[swzK(nf * 16 + lr, kf * 32 + lk)];
        sacc[nf] = __builtin_amdgcn_mfma_f32_16x16x32_bf16(
            qf[kf], kfr, sacc[nf], 0, 0, 0);
      }

    // ---- scale + mask (exp2 domain) ----
    #pragma unroll
    for (int nf = 0; nf < 8; ++nf)
      #pragma unroll
      for (int i = 0; i < 4; ++i)
        sacc[nf][i] = sacc[nf][i] * SCL + mk[nf];

    // ---- row max ----
    float pm[4];
    #pragma unroll
    for (int i = 0; i < 4; ++i) {
      float rm = fmaxf(fmaxf(fmaxf(sacc[0][i], sacc[1][i]),
                             fmaxf(sacc[2][i], sacc[3][i])),
                       fmaxf(fmaxf(sacc[4][i], sacc[5][i]),
                             fmaxf(sacc[6][i], sacc[7][i])));
      rm = fmaxf(rm, __shfl_xor(rm, 1));
      rm = fmaxf(rm, __shfl_xor(rm, 2));
      rm = fmaxf(rm, __shfl_xor(rm, 4));
      rm = fmaxf(rm, __shfl_xor(rm, 8));
      pm[i] = rm;
    }

    // ---- defer-max (T13): rescale only if some row grew > 2^8 ----
    int small = (pm[0] - m_i[0] <= 8.f) & (pm[1] - m_i[1] <= 8.f) &
                (pm[2] - m_i[2] <= 8.f) & (pm[3] - m_i[3] <= 8.f);
    if (!__all(small)) {
      #pragma unroll
      for (int i = 0; i < 4; ++i) {
        float mn = fmaxf(m_i[i], pm[i]);
        float al = fexp2(m_i[i] - mn);
        m_i[i] = mn;
        l_i[i] *= al;
        #pragma unroll
        for (int nf = 0; nf < 4; ++nf) cacc[nf][i] *= al;
      }
    }

    // ---- exp + row sum ----
    #pragma unroll
    for (int i = 0; i < 4; ++i) {
      float rs = 0.f;
      #pragma unroll
      for (int nf = 0; nf < 8; ++nf) {
        float pv = fexp2(sacc[nf][i] - m_i[i]);
        sacc[nf][i] = pv;
        rs += pv;
      }
      rs += __shfl_xor(rs, 1);
      rs += __shfl_xor(rs, 2);
      rs += __shfl_xor(rs, 4);
      rs += __shfl_xor(rs, 8);
      l_i[i] += rs;
    }

    // ---- PV in two 64-col halves through the wave-private P stripe ----
    #pragma unroll
    for (int half = 0; half < 2; ++half) {
      #pragma unroll
      for (int nf4 = 0; nf4 < 4; ++nf4)
        #pragma unroll
        for (int i = 0; i < 4; ++i)
          QP[swzK(w * 16 + g * 4 + i, nf4 * 16 + lr)] =
              f2bf(sacc[half * 4 + nf4][i]);

      bf16x8 pa[2];
      pa[0] = *(const bf16x8*)&QP[swzK(w * 16 + lr, lk)];
      pa[1] = *(const bf16x8*)&QP[swzK(w * 16 + lr, 32 + lk)];
      #pragma unroll
      for (int kf = 0; kf < 2; ++kf)
        #pragma unroll
        for (int nf = 0; nf < 4; ++nf) {
          bf16x8 vf = *(const bf16x8*)&XTs[swzT(nf * 16 + lr,
                                                half * 64 + kf * 32 + lk)];
          cacc[nf] = __builtin_amdgcn_mfma_f32_16x16x32_bf16(
              pa[kf], vf, cacc[nf], 0, 0, 0);
        }
    }
    __syncthreads();  // Xs/XTs reads done before next phase's writes
  }

  // ---- normalize + store ----
  #pragma unroll
  for (int i = 0; i < 4; ++i) {
    float inv = __builtin_amdgcn_rcpf(l_i[i]);
    #pragma unroll
    for (int nf = 0; nf < 4; ++nf) {
      int row = q0 + w * 16 + g * 4 + i;
      int col = h * DHEAD + nf * 16 + lr;
      out[((size_t)b * SEQ + row) * D_MODEL + col] = cacc[nf][i] * inv;
    }
  }
}

// ---------------------------------------------------------------------------
extern "C" void kernel_launch(void* const* d_in, const int* in_sizes, int n_in,
                              void* d_out, int out_size, void* d_ws, size_t ws_size,
                              hipStream_t stream) {
  const float* x    = (const float*)d_in[0];
  const float* mask = (const float*)d_in[1];
  const float* W    = (const float*)d_in[2];
  const float* bias = (const float*)d_in[3];
  float* out        = (float*)d_out;

  unsigned short* mixed  = (unsigned short*)d_ws;          // 12.58 MB
  unsigned short* mixedT = mixed + (size_t)8192 * D_MODEL; // 12.58 MB
  const size_t need = (size_t)8192 * D_MODEL * 2 * 2;
  const bool preT = ws_size >= need;

  dim3 gp(8192 / 128, D_MODEL / 128);             // (64, 6)
  const int nblk = (SEQ / QB) * NHEAD * BATCH;    // 1536 = 8 XCD * 192

  if (preT) {
    proj_kernel<true><<<gp, 256, 0, stream>>>(x, W, bias, mixed, mixedT);
    attn_kernel<true><<<nblk, 256, 0, stream>>>(mixed, mixedT, mask, out);
  } else {
    proj_kernel<false><<<gp, 256, 0, stream>>>(x, W, bias, mixed, mixed);
    attn_kernel<false><<<nblk, 256, 0, stream>>>(mixed, mixed, mask, out);
  }
}

// Round 6
// 115.682 us; speedup vs baseline: 1.6343x; 1.6343x over previous
//
#include <hip/hip_runtime.h>
#include <hip/hip_bf16.h>

// BERT self-attention, B=8 S=1024 D=768 H=12 DH=64, fp32 in/out.
// (1) bf16 MFMA projection GEMM -> mixed (row-major) + mixedT ([b][h][d][t]).
// (2) flash attention: QB=64, KVB=64 (R4 structure: VGPR 60, no spill),
//     XOR-swizzled LDS (0 conflicts), reg-prefetch (T14),
//     XCD-grouped block swizzle (T1), defer-max (T13), exp2 softmax.

#define D_MODEL 768
#define SEQ     1024
#define NHEAD   12
#define DHEAD   64
#define BATCH   8
#define QB      64
#define LOG2E   1.44269504088896f

typedef __attribute__((ext_vector_type(8))) short bf16x8;
typedef __attribute__((ext_vector_type(4))) short short4v;
typedef __attribute__((ext_vector_type(4))) float f32x4;

__device__ __forceinline__ unsigned short f2bf(float f) {
  __hip_bfloat16 h = __float2bfloat16(f);
  return *reinterpret_cast<unsigned short*>(&h);
}

__device__ __forceinline__ float fexp2(float x) {
#if __has_builtin(__builtin_amdgcn_exp2f)
  return __builtin_amdgcn_exp2f(x);
#else
  return exp2f(x);
#endif
}

// 64-wide bf16 tile: elem-index XOR swizzle (16B granule x row)
__device__ __forceinline__ int lswz(int r, int c) {
  return (r << 6) + (c ^ ((r & 7) << 3));
}

// ---------------------------------------------------------------------------
// Projection GEMM: mixed = bf16(X @ W^T + b); also mixedT (per-head [d][t]).
// ---------------------------------------------------------------------------
template<bool WRITE_T>
__global__ __launch_bounds__(256) void proj_kernel(
    const float* __restrict__ X, const float* __restrict__ W,
    const float* __restrict__ bias, unsigned short* __restrict__ mixed,
    unsigned short* __restrict__ mixedT)
{
  __shared__ unsigned short As[128][40];
  __shared__ unsigned short Bs[128][40];

  const int tid = threadIdx.x;
  const int l   = tid & 63;
  const int w   = tid >> 6;
  const int m0  = blockIdx.x * 128;
  const int n0  = blockIdx.y * 128;
  const int wm  = (w >> 1) * 64;
  const int wn  = (w & 1) * 64;
  const int lr  = l & 15;
  const int g   = l >> 4;
  const int lk  = g * 8;

  f32x4 acc[4][4] = {};

  for (int k0 = 0; k0 < D_MODEL; k0 += 32) {
    #pragma unroll
    for (int rr = 0; rr < 4; ++rr) {
      int p   = tid + rr * 256;
      int row = p >> 3;
      int cg  = (p & 7) * 4;
      f32x4 a  = *(const f32x4*)&X[(size_t)(m0 + row) * D_MODEL + k0 + cg];
      f32x4 bv = *(const f32x4*)&W[(size_t)(n0 + row) * D_MODEL + k0 + cg];
      short4v ap, bp;
      #pragma unroll
      for (int jj = 0; jj < 4; ++jj) { ap[jj] = (short)f2bf(a[jj]); bp[jj] = (short)f2bf(bv[jj]); }
      *(short4v*)&As[row][cg] = ap;
      *(short4v*)&Bs[row][cg] = bp;
    }
    __syncthreads();

    bf16x8 af[4], bfr[4];
    #pragma unroll
    for (int am = 0; am < 4; ++am) af[am]  = *(const bf16x8*)&As[wm + am * 16 + lr][lk];
    #pragma unroll
    for (int bn = 0; bn < 4; ++bn) bfr[bn] = *(const bf16x8*)&Bs[wn + bn * 16 + lr][lk];

    #pragma unroll
    for (int am = 0; am < 4; ++am)
      #pragma unroll
      for (int bn = 0; bn < 4; ++bn)
        acc[am][bn] = __builtin_amdgcn_mfma_f32_16x16x32_bf16(
            af[am], bfr[bn], acc[am][bn], 0, 0, 0);
    __syncthreads();
  }

  const int orow = g * 4;
  const int bT   = m0 >> 10;
  const int tl0  = (m0 & 1023) + wm + orow;
  #pragma unroll
  for (int bn = 0; bn < 4; ++bn) {
    int   col  = n0 + wn + bn * 16 + lr;
    float bcol = bias[col];
    size_t tbase = ((size_t)bT * D_MODEL + col) * SEQ;
    #pragma unroll
    for (int am = 0; am < 4; ++am) {
      short4v pk;
      #pragma unroll
      for (int i = 0; i < 4; ++i) {
        float v = acc[am][bn][i] + bcol;
        unsigned short hv = f2bf(v);
        mixed[(size_t)(m0 + wm + am * 16 + orow + i) * D_MODEL + col] = hv;
        pk[i] = (short)hv;
      }
      if (WRITE_T)
        *(short4v*)&mixedT[tbase + tl0 + am * 16] = pk;
    }
  }
}

// ---------------------------------------------------------------------------
// Fused attention (R4 structure + T1 XCD grouping + T13 defer-max).
// ---------------------------------------------------------------------------
template<bool PRE_T>
__global__ __launch_bounds__(256, 4) void attn_kernel(
    const unsigned short* __restrict__ mixed,
    const unsigned short* __restrict__ mixedT,
    const float* __restrict__ mask, float* __restrict__ out)
{
  __shared__ unsigned short QP[QB * DHEAD];   // Q tile; later per-wave P stripes
  __shared__ unsigned short Xs[64 * DHEAD];   // K rows
  __shared__ unsigned short XTs[DHEAD * 64];  // V^T rows

  const int tid = threadIdx.x;
  const int l   = tid & 63;
  const int w   = tid >> 6;
  const int lr  = l & 15;
  const int g   = l >> 4;
  const int lk  = g * 8;

  // T1: XCD-grouped decode — all 16 q-tiles of one (b,h) share id mod 8.
  const int id  = blockIdx.x;          // 0..1535
  const int xcd = id & 7;
  const int j   = id >> 3;             // 0..191
  const int pr  = xcd * 12 + (j >> 4); // (b,h) pair, bijective over 96
  const int q0  = (j & 15) * QB;
  const int h   = pr % NHEAD;
  const int b   = pr / NHEAD;

  const size_t base  = ((size_t)b * SEQ) * D_MODEL + h * DHEAD;
  const size_t baseT = ((size_t)b * D_MODEL + h * DHEAD) * SEQ;

  const int srow = tid >> 3;          // 0..31 (+32 second pass)
  const int scol = (tid & 7) * 8;

  // ---- stage Q (64x64) ----
  #pragma unroll
  for (int rr = 0; rr < 2; ++rr) {
    int row = srow + rr * 32;
    bf16x8 v = *(const bf16x8*)&mixed[base + (size_t)(q0 + row) * D_MODEL + scol];
    *(bf16x8*)&QP[lswz(row, scol)] = v;
  }

  // ---- prefetch tile 0 ----
  bf16x8 xr[2], xtr[2];
  #pragma unroll
  for (int rr = 0; rr < 2; ++rr) {
    int row = srow + rr * 32;
    xr[rr] = *(const bf16x8*)&mixed[base + (size_t)row * D_MODEL + scol];
    if (PRE_T)
      xtr[rr] = *(const bf16x8*)&mixedT[baseT + (size_t)row * SEQ + scol];
  }

  __syncthreads();
  bf16x8 qf[2];
  qf[0] = *(const bf16x8*)&QP[lswz(w * 16 + lr, lk)];
  qf[1] = *(const bf16x8*)&QP[lswz(w * 16 + lr, 32 + lk)];
  // QP rows [w*16, w*16+16) are wave-private P storage from here on.

  float m_i[4], l_i[4];
  f32x4 cacc[4] = {};
  #pragma unroll
  for (int i = 0; i < 4; ++i) { m_i[i] = -1e30f; l_i[i] = 0.f; }

  const float SCL = 0.125f * LOG2E;

  for (int t0 = 0; t0 < SEQ; t0 += 64) {
    // ---- write prefetched regs -> LDS ----
    #pragma unroll
    for (int rr = 0; rr < 2; ++rr) {
      int row = srow + rr * 32;
      *(bf16x8*)&Xs[lswz(row, scol)] = xr[rr];
      if (PRE_T) {
        *(bf16x8*)&XTs[lswz(row, scol)] = xtr[rr];
      } else {
        #pragma unroll
        for (int jj = 0; jj < 8; ++jj)
          XTs[lswz(scol + jj, row)] = (unsigned short)xr[rr][jj];
      }
    }
    __syncthreads();

    // ---- issue next tile's prefetch ----
    if (t0 + 64 < SEQ) {
      #pragma unroll
      for (int rr = 0; rr < 2; ++rr) {
        int row = srow + rr * 32;
        xr[rr] = *(const bf16x8*)&mixed[base + (size_t)(t0 + 64 + row) * D_MODEL + scol];
        if (PRE_T)
          xtr[rr] = *(const bf16x8*)&mixedT[baseT + (size_t)row * SEQ + t0 + 64 + scol];
      }
    }

    float mk[4];
    #pragma unroll
    for (int nf = 0; nf < 4; ++nf)
      mk[nf] = mask[(size_t)b * SEQ + t0 + nf * 16 + lr] * LOG2E;

    // ---- S = Q @ K^T ----
    f32x4 sacc[4] = {};
    #pragma unroll
    for (int kf = 0; kf < 2; ++kf)
      #pragma unroll
      for (int nf = 0; nf < 4; ++nf) {
        bf16x8 kfr = *(const bf16x8*)&Xs[lswz(nf * 16 + lr, kf * 32 + lk)];
        sacc[nf] = __builtin_amdgcn_mfma_f32_16x16x32_bf16(
            qf[kf], kfr, sacc[nf], 0, 0, 0);
      }

    // ---- scale + mask (exp2 domain) ----
    #pragma unroll
    for (int nf = 0; nf < 4; ++nf)
      #pragma unroll
      for (int i = 0; i < 4; ++i)
        sacc[nf][i] = sacc[nf][i] * SCL + mk[nf];

    // ---- row max ----
    float pm[4];
    #pragma unroll
    for (int i = 0; i < 4; ++i) {
      float rm = fmaxf(fmaxf(sacc[0][i], sacc[1][i]),
                       fmaxf(sacc[2][i], sacc[3][i]));
      rm = fmaxf(rm, __shfl_xor(rm, 1));
      rm = fmaxf(rm, __shfl_xor(rm, 2));
      rm = fmaxf(rm, __shfl_xor(rm, 4));
      rm = fmaxf(rm, __shfl_xor(rm, 8));
      pm[i] = rm;
    }

    // ---- T13 defer-max: rescale only when a row max grew > 2^8 ----
    int small = (pm[0] - m_i[0] <= 8.f) & (pm[1] - m_i[1] <= 8.f) &
                (pm[2] - m_i[2] <= 8.f) & (pm[3] - m_i[3] <= 8.f);
    if (!__all(small)) {
      #pragma unroll
      for (int i = 0; i < 4; ++i) {
        float mn = fmaxf(m_i[i], pm[i]);
        float al = fexp2(m_i[i] - mn);
        m_i[i] = mn;
        l_i[i] *= al;
        #pragma unroll
        for (int nf = 0; nf < 4; ++nf) cacc[nf][i] *= al;
      }
    }

    // ---- exp + row sum ----
    #pragma unroll
    for (int i = 0; i < 4; ++i) {
      float rs = 0.f;
      #pragma unroll
      for (int nf = 0; nf < 4; ++nf) {
        float pv = fexp2(sacc[nf][i] - m_i[i]);
        sacc[nf][i] = pv;
        rs += pv;
      }
      rs += __shfl_xor(rs, 1);
      rs += __shfl_xor(rs, 2);
      rs += __shfl_xor(rs, 4);
      rs += __shfl_xor(rs, 8);
      l_i[i] += rs;
    }

    // ---- P -> own QP stripe (wave-private) ----
    #pragma unroll
    for (int nf = 0; nf < 4; ++nf)
      #pragma unroll
      for (int i = 0; i < 4; ++i)
        QP[lswz(w * 16 + g * 4 + i, nf * 16 + lr)] = f2bf(sacc[nf][i]);

    // ---- ctx += P @ V ----
    bf16x8 pa[2];
    pa[0] = *(const bf16x8*)&QP[lswz(w * 16 + lr, lk)];
    pa[1] = *(const bf16x8*)&QP[lswz(w * 16 + lr, 32 + lk)];
    #pragma unroll
    for (int kf = 0; kf < 2; ++kf)
      #pragma unroll
      for (int nf = 0; nf < 4; ++nf) {
        bf16x8 vf = *(const bf16x8*)&XTs[lswz(nf * 16 + lr, kf * 32 + lk)];
        cacc[nf] = __builtin_amdgcn_mfma_f32_16x16x32_bf16(
            pa[kf], vf, cacc[nf], 0, 0, 0);
      }
    __syncthreads();  // Xs/XTs reads done before next iter's writes
  }

  // ---- normalize + store ----
  #pragma unroll
  for (int i = 0; i < 4; ++i) {
    float inv = __builtin_amdgcn_rcpf(l_i[i]);
    #pragma unroll
    for (int nf = 0; nf < 4; ++nf) {
      int row = q0 + w * 16 + g * 4 + i;
      int col = h * DHEAD + nf * 16 + lr;
      out[((size_t)b * SEQ + row) * D_MODEL + col] = cacc[nf][i] * inv;
    }
  }
}

// ---------------------------------------------------------------------------
extern "C" void kernel_launch(void* const* d_in, const int* in_sizes, int n_in,
                              void* d_out, int out_size, void* d_ws, size_t ws_size,
                              hipStream_t stream) {
  const float* x    = (const float*)d_in[0];
  const float* mask = (const float*)d_in[1];
  const float* W    = (const float*)d_in[2];
  const float* bias = (const float*)d_in[3];
  float* out        = (float*)d_out;

  unsigned short* mixed  = (unsigned short*)d_ws;          // 12.58 MB
  unsigned short* mixedT = mixed + (size_t)8192 * D_MODEL; // 12.58 MB
  const size_t need = (size_t)8192 * D_MODEL * 2 * 2;
  const bool preT = ws_size >= need;

  dim3 gp(8192 / 128, D_MODEL / 128);             // (64, 6)
  const int nblk = (SEQ / QB) * NHEAD * BATCH;    // 1536 = 8 * 192

  if (preT) {
    proj_kernel<true><<<gp, 256, 0, stream>>>(x, W, bias, mixed, mixedT);
    attn_kernel<true><<<nblk, 256, 0, stream>>>(mixed, mixedT, mask, out);
  } else {
    proj_kernel<false><<<gp, 256, 0, stream>>>(x, W, bias, mixed, mixed);
    attn_kernel<false><<<nblk, 256, 0, stream>>>(mixed, mixed, mask, out);
  }
}